// Round 12
// baseline (56.430 us; speedup 1.0000x reference)
//
#include <hip/hip_runtime.h>

#define BATCH 8192
#define DIM 128
#define NREL 1000
#define MARGIN 1.0f
#define NSPLIT 4
#define GRID (NREL * NSPLIT)  // 4000 = 8 XCDs * 125 relations * 4 splits

// ws layout (4 B units): partial4[32768] | start[1024] | order[8192]
#define WS_PARTIAL 0
#define WS_START   32768
#define WS_ORDER   33792

// Single-block counting sort, exact offsets (proven R11).
__global__ __launch_bounds__(1024) void sort_kernel(const int* __restrict__ r_idx,
                                                    int* __restrict__ start_g,
                                                    int* __restrict__ order) {
  __shared__ int s_cnt[1024];
  __shared__ int s_cur[1024];
  __shared__ int s_wsum[16];
  const int tid = threadIdx.x, lane = tid & 63, wave = tid >> 6;
  s_cnt[tid] = 0;
  __syncthreads();
  int my[8];
#pragma unroll
  for (int k = 0; k < 8; ++k) {
    my[k] = r_idx[tid + k * 1024];
    atomicAdd(&s_cnt[my[k]], 1);
  }
  __syncthreads();
  const int c = s_cnt[tid];
  int v = c;
#pragma unroll
  for (int o = 1; o < 64; o <<= 1) {
    int u = __shfl_up(v, o, 64);
    if (lane >= o) v += u;
  }
  if (lane == 63) s_wsum[wave] = v;
  __syncthreads();
  int woff = 0;
  for (int w = 0; w < wave; ++w) woff += s_wsum[w];
  const int my_start = woff + v - c;
  start_g[tid] = my_start;  // bins >= NREL are empty -> start[1000] == 8192
  s_cur[tid] = my_start;
  __syncthreads();
#pragma unroll
  for (int k = 0; k < 8; ++k) {
    int p = atomicAdd(&s_cur[my[k]], 1);
    order[p] = tid + k * 1024;
  }
}

__device__ inline float2 dvec(const float* __restrict__ b, int c0) {
  float2 h = *(const float2*)(b + c0);
  float2 r = *(const float2*)(b + DIM + c0);
  float2 t = *(const float2*)(b + 2 * DIM + c0);
  return make_float2(fabsf(h.x + r.x - t.x), fabsf(h.y + r.y - t.y));
}

// NSPLIT=4 blocks per relation; block (r, s) covers W rows [32s, 32s+32),
// wave w covers rows [32s+8w, 32s+8w+8) -> 4 float4 W loads per chunk.
// W traffic is COMPULSORY (each row-segment read by exactly one block);
// d re-reads are same-XCD L2 hits. Chunks of 8 elements looped per block.
// d staged cooperatively (wave w -> slots 2w,2w+1) in the proven stride-36
// unit layout: unit l (rows 2l,2l+1): [0:8) dp r2l | [8:16) dn r2l |
// [16:24) dp r2l+1 | [24:32) dn r2l+1 | pad4. Loop reads = 2-addr broadcast.
__global__ __launch_bounds__(256, 4) void score_kernel(
    const float* __restrict__ pos_b, const float* __restrict__ neg_b,
    const float* __restrict__ rel_emb, const int* __restrict__ start,
    const int* __restrict__ order, float* __restrict__ partial4) {
  __shared__ float s_d[64 * 36];  // 9216 B: full 128-row d for 8 elems
  __shared__ float s_ps[4][8];
  const int tid = threadIdx.x, lane = tid & 63, wave = tid >> 6;
  // XCD-coherent mapping: all 4 split-blocks of a relation on ONE XCD,
  // 125 consecutive relations per XCD. p&7 = XCD (round-robin dispatch).
  const int p = blockIdx.x;
  const int r = (p & 7) * (NREL / 8) + (p >> 5);
  const int seg = (p >> 3) & 3;
  const int sA = start[r], sB = start[r + 1];
  if (sA == sB) return;  // block-uniform empty relation

  const int c0 = lane * 2;
  const int lam = lane & 31, rsel = lane >> 5;
  const int colb = lam * 4;
  const float* W = rel_emb + (size_t)r * (DIM * DIM) +
                   (size_t)(seg * 32 + wave * 8 + rsel) * DIM + colb;
  // row = seg*32 + wave*8 + 2*it + rsel -> unit = seg*16 + wave*4 + it
  const float* dbase = s_d + (seg * 16 + wave * 4) * 36 + rsel * 16;

  for (int base = sA; base < sB; base += 8) {
    const int rem = sB - base;
    const int mm = rem < 8 ? rem : 8;

    // ---- cooperative d-stage: wave w fills slots 2w, 2w+1 ----
    {
      const int iA = 2 * wave, iB = iA + 1;
      const bool vA = iA < mm, vB = iB < mm;
      const float2 z = make_float2(0.f, 0.f);
      const int eA = vA ? order[base + iA] : 0;
      const int eB = vB ? order[base + iB] : 0;
      float2 dpA = vA ? dvec(pos_b + (size_t)eA * 3 * DIM, c0) : z;
      float2 dnA = vA ? dvec(neg_b + (size_t)eA * 3 * DIM, c0) : z;
      float2 dpB = vB ? dvec(pos_b + (size_t)eB * 3 * DIM, c0) : z;
      float2 dnB = vB ? dvec(neg_b + (size_t)eB * 3 * DIM, c0) : z;
      float* u = s_d + lane * 36;
      const int s2 = 2 * wave;
      *(float2*)(u + s2)      = make_float2(dpA.x, dpB.x);
      *(float2*)(u + 8 + s2)  = make_float2(dnA.x, dnB.x);
      *(float2*)(u + 16 + s2) = make_float2(dpA.y, dpB.y);
      *(float2*)(u + 24 + s2) = make_float2(dnA.y, dnB.y);
    }
    __syncthreads();

    // ---- FMA loop: wave's 8-row slice of this block's 32-row segment ----
    const float4 fz = make_float4(0.f, 0.f, 0.f, 0.f);
    float4 ap[8], an[8];
#pragma unroll
    for (int i = 0; i < 8; ++i) { ap[i] = fz; an[i] = fz; }

#define FMA4(ACC, D, WV)          \
  ACC.x = fmaf(D, WV.x, ACC.x);   \
  ACC.y = fmaf(D, WV.y, ACC.y);   \
  ACC.z = fmaf(D, WV.z, ACC.z);   \
  ACC.w = fmaf(D, WV.w, ACC.w);

#pragma unroll
    for (int it = 0; it < 4; ++it) {
      float4 wv = *(const float4*)(W + (size_t)(it * 2) * DIM);
      const float* dd = dbase + it * 36;
      float4 p0 = *(const float4*)(dd + 0);   // broadcast
      float4 p1 = *(const float4*)(dd + 4);   // broadcast
      float4 n0 = *(const float4*)(dd + 8);   // broadcast
      float4 n1 = *(const float4*)(dd + 12);  // broadcast
      FMA4(ap[0], p0.x, wv) FMA4(ap[1], p0.y, wv)
      FMA4(ap[2], p0.z, wv) FMA4(ap[3], p0.w, wv)
      FMA4(ap[4], p1.x, wv) FMA4(ap[5], p1.y, wv)
      FMA4(ap[6], p1.z, wv) FMA4(ap[7], p1.w, wv)
      FMA4(an[0], n0.x, wv) FMA4(an[1], n0.y, wv)
      FMA4(an[2], n0.z, wv) FMA4(an[3], n0.w, wv)
      FMA4(an[4], n1.x, wv) FMA4(an[5], n1.y, wv)
      FMA4(an[6], n1.z, wv) FMA4(an[7], n1.w, wv)
    }
#undef FMA4

    // ---- epilogue: dot colaccs with d (LDS reads; measured cheap) ----
    float s[8];
#pragma unroll
    for (int i = 0; i < 8; ++i) s[i] = 0.f;
#define EPI(K, COMP)                                              \
    {                                                             \
      const int cc = colb + K;                                    \
      const float* dd = s_d + (cc >> 1) * 36 + (cc & 1) * 16;     \
      float4 plo = *(const float4*)(dd + 0);                      \
      float4 phi = *(const float4*)(dd + 4);                      \
      float4 nlo = *(const float4*)(dd + 8);                      \
      float4 nhi = *(const float4*)(dd + 12);                     \
      s[0] += ap[0].COMP * plo.x - an[0].COMP * nlo.x;            \
      s[1] += ap[1].COMP * plo.y - an[1].COMP * nlo.y;            \
      s[2] += ap[2].COMP * plo.z - an[2].COMP * nlo.z;            \
      s[3] += ap[3].COMP * plo.w - an[3].COMP * nlo.w;            \
      s[4] += ap[4].COMP * phi.x - an[4].COMP * nhi.x;            \
      s[5] += ap[5].COMP * phi.y - an[5].COMP * nhi.y;            \
      s[6] += ap[6].COMP * phi.z - an[6].COMP * nhi.z;            \
      s[7] += ap[7].COMP * phi.w - an[7].COMP * nhi.w;            \
    }
    EPI(0, x) EPI(1, y) EPI(2, z) EPI(3, w)
#undef EPI

#pragma unroll
    for (int o = 32; o > 0; o >>= 1) {
#pragma unroll
      for (int i = 0; i < 8; ++i) s[i] += __shfl_xor(s[i], o, 64);
    }
    if (lane == 0) {
#pragma unroll
      for (int i = 0; i < 8; ++i) s_ps[wave][i] = s[i];
    }
    __syncthreads();
    if (tid < mm)
      partial4[order[base + tid] * 4 + seg] =
          s_ps[0][tid] + s_ps[1][tid] + s_ps[2][tid] + s_ps[3][tid];
    // s_ps only rewritten after next chunk's post-stage barrier -> safe.
  }
}

__global__ __launch_bounds__(256) void reduce_kernel(const float* __restrict__ partial4,
                                                     float* __restrict__ out) {
  float acc = 0.f;
  for (int i = threadIdx.x; i < BATCH; i += 256) {
    float4 q = *(const float4*)(partial4 + i * 4);
    float v = MARGIN + q.x + q.y + q.z + q.w;
    acc += (v > 0.f) ? v : 0.f;
  }
#pragma unroll
  for (int o = 32; o > 0; o >>= 1) acc += __shfl_xor(acc, o, 64);
  __shared__ float s[4];
  const int lane = threadIdx.x & 63, wave = threadIdx.x >> 6;
  if (lane == 0) s[wave] = acc;
  __syncthreads();
  if (threadIdx.x == 0) out[0] = (s[0] + s[1] + s[2] + s[3]) * (1.0f / BATCH);
}

extern "C" void kernel_launch(void* const* d_in, const int* in_sizes, int n_in,
                              void* d_out, int out_size, void* d_ws, size_t ws_size,
                              hipStream_t stream) {
  const float* pos_b = (const float*)d_in[0];
  const float* neg_b = (const float*)d_in[1];
  const int* r_idx = (const int*)d_in[2];
  const float* rel_emb = (const float*)d_in[3];
  float* out = (float*)d_out;

  float* partial4 = (float*)d_ws + WS_PARTIAL;
  int* start = (int*)d_ws + WS_START;
  int* order = (int*)d_ws + WS_ORDER;

  sort_kernel<<<1, 1024, 0, stream>>>(r_idx, start, order);
  score_kernel<<<GRID, 256, 0, stream>>>(pos_b, neg_b, rel_emb, start, order,
                                         partial4);
  reduce_kernel<<<1, 256, 0, stream>>>(partial4, out);
}